// Round 4
// baseline (55.347 us; speedup 1.0000x reference)
//
#include <hip/hip_runtime.h>
#include <hip/hip_bf16.h>

#define HDIM 2048
#define HH (HDIM * HDIM)          // 4,194,304 pixels per plane
#define NBINS 256
#define KCNT 1048576.0f           // K_SRC == K_TAR == HH/4 (exactly 2^20)
#define TOTAL_ELEMS 12582912.0    // 3 * H * H

// Pack layout for src bins: bits [63:40] = count, bits [39:0] = sum(frac * 2^25).
// Per block (>=2048 px): count <= 6144 < 2^24; fracsum <= 6144*2^25 < 2^38 < 2^40.
#define FRAC_SCALE 33554432.0f    // 2^25
#define FRAC_INV   (1.0 / 33554432.0)
#define FRAC_MASK  ((1ull << 40) - 1)

// Per-block partial row: 768 u64 (src: packed count|fracsum) + 768 u32 (tar counts)
#define ROW_U64    1152           // row size in u64 units (768 + 768/2)
#define ROW_BYTES  9216
#define TAIL_BYTES (1536 * sizeof(int) + 768 * sizeof(unsigned long long))  // 12288
#define ROWS_PER_CHUNK 32

__device__ __forceinline__ float de_norm255(float x) {
    float v = (x + 1.0f) * 0.5f;               // /2.0 == *0.5 exactly in f32
    v = fminf(fmaxf(v, 0.0f), 1.0f) * 255.0f;  // in [0, 255]
    return v;
}

// Kernel 1: branchless per-block histograms.
// Every lane issues an unconditional LDS atomic; inactive (masked-out or
// clipped) lanes are steered to dummy[lane] by a cndmask on the ADDRESS —
// no exec-mask branches, no same-address hot-bin contention.
__global__ void hist_kernel(const float* __restrict__ inp,
                            const float* __restrict__ tar,
                            const float* __restrict__ msrc,
                            const float* __restrict__ mtar,
                            unsigned long long* __restrict__ parts) {
    __shared__ unsigned long long h64[3 * NBINS];   // src: packed count|fracsum
    __shared__ unsigned long long dummy64[64];      // per-lane trash slots
    __shared__ unsigned int       h32[3 * NBINS];   // tar: counts
    for (int i = threadIdx.x; i < 3 * NBINS; i += blockDim.x) {
        h64[i] = 0ull;
        h32[i] = 0u;
    }
    if (threadIdx.x < 64) dummy64[threadIdx.x] = 0ull;
    __syncthreads();

    const int lane = threadIdx.x & 63;
    unsigned long long* const dslot = &dummy64[lane];

    int nz[6] = {0, 0, 0, 0, 0, 0};   // v==0   counts (rows 0-2 src, 3-5 tar)
    int nf[6] = {0, 0, 0, 0, 0, 0};   // v==255 counts

    const int stride = gridDim.x * blockDim.x;
    const int n4 = HH / 4;
    for (int p4 = blockIdx.x * blockDim.x + threadIdx.x; p4 < n4; p4 += stride) {
        float4 ms4 = ((const float4*)msrc)[p4];
        float4 mt4 = ((const float4*)mtar)[p4];
        float m[4] = {ms4.x, ms4.y, ms4.z, ms4.w};
        float t[4] = {mt4.x, mt4.y, mt4.z, mt4.w};
        #pragma unroll
        for (int c = 0; c < 3; ++c) {
            float4 v4 = ((const float4*)(inp + (size_t)c * HH))[p4];
            float4 w4 = ((const float4*)(tar + (size_t)c * HH))[p4];
            float vv[4] = {v4.x, v4.y, v4.z, v4.w};
            float ww[4] = {w4.x, w4.y, w4.z, w4.w};
            #pragma unroll
            for (int k = 0; k < 4; ++k) {
                // --- src ---
                {
                    const bool on = (m[k] != 0.0f);
                    float v = de_norm255(vv[k]);
                    int b = (int)v;                       // trunc, 0..255
                    float frac = v - (float)b;            // exact in f32
                    unsigned fx = (unsigned)(frac * FRAC_SCALE);
                    const bool mid = on & (v > 0.0f) & (v < 255.0f);
                    unsigned long long* addr = mid ? &h64[c * NBINS + b] : dslot;
                    atomicAdd(addr, (1ull << 40) | (unsigned long long)fx);
                    nz[c] += (int)(on & (v == 0.0f));
                    nf[c] += (int)(on & (v == 255.0f));
                }
                // --- tar ---
                {
                    const bool on = (t[k] != 0.0f);
                    float w = de_norm255(ww[k]);
                    int b = (int)w;
                    const bool mid = on & (w > 0.0f) & (w < 255.0f);
                    unsigned int* addr = mid ? &h32[c * NBINS + b]
                                             : (unsigned int*)dslot;
                    atomicAdd(addr, 1u);
                    nz[3 + c] += (int)(on & (w == 0.0f));
                    nf[3 + c] += (int)(on & (w == 255.0f));
                }
            }
        }
    }

    // wave-reduce the 12 clipped-value counters, one LDS atomic per wave each
    #pragma unroll
    for (int j = 0; j < 6; ++j) {
        int a = nz[j], f = nf[j];
        #pragma unroll
        for (int off = 32; off > 0; off >>= 1) {
            a += __shfl_down(a, off, 64);
            f += __shfl_down(f, off, 64);
        }
        if (lane == 0) {
            if (j < 3) {
                if (a) atomicAdd(&h64[j * NBINS + 0],
                                 ((unsigned long long)a) << 40);
                if (f) atomicAdd(&h64[j * NBINS + NBINS - 1],
                                 ((unsigned long long)f) << 40);
            } else {
                if (a) atomicAdd(&h32[(j - 3) * NBINS + 0], (unsigned)a);
                if (f) atomicAdd(&h32[(j - 3) * NBINS + NBINS - 1], (unsigned)f);
            }
        }
    }
    __syncthreads();

    // coalesced flush of this block's partial row (full overwrite -> no memset)
    unsigned long long* row64 = parts + (size_t)blockIdx.x * ROW_U64;
    for (int i = threadIdx.x; i < 3 * NBINS; i += blockDim.x)
        row64[i] = h64[i];
    unsigned int* row32 = (unsigned int*)(row64 + 3 * NBINS);
    for (int i = threadIdx.x; i < 3 * NBINS; i += blockDim.x)
        row32[i] = h32[i];
}

// Kernel 2: column reduction over row-chunks; integer atomics -> deterministic.
__global__ void reduce_kernel(const unsigned long long* __restrict__ parts,
                              int nblk,
                              int* __restrict__ counts,              // [1536]
                              unsigned long long* __restrict__ fracs) { // [768]
    const int j = blockIdx.x * blockDim.x + threadIdx.x;   // column 0..1535
    if (j >= 1536) return;
    int w0 = blockIdx.y * ROWS_PER_CHUNK;
    int w1 = w0 + ROWS_PER_CHUNK;
    if (w1 > nblk) w1 = nblk;
    if (w0 >= w1) return;

    if (j < 768) {
        unsigned long long cnt = 0, fr = 0;
        for (int w = w0; w < w1; ++w) {
            unsigned long long p = parts[(size_t)w * ROW_U64 + j];
            cnt += p >> 40;
            fr  += p & FRAC_MASK;
        }
        if (cnt) atomicAdd(&counts[j], (int)cnt);
        if (fr)  atomicAdd(&fracs[j], fr);
    } else {
        const unsigned int* p32 = (const unsigned int*)parts;
        int cnt = 0;
        const int jj = j - 768;
        for (int w = w0; w < w1; ++w)
            cnt += p32[(size_t)w * (2 * ROW_U64) + 1536 + jj];
        if (cnt) atomicAdd(&counts[768 + jj], cnt);
    }
}

// Kernel 3: cdf (bit-exact serial f32 cumsum) + searchsorted table + analytic loss.
// Within bin b, v in [b, b+1) and t integer => |v-t| sign fixed per bin:
//   t <= b : sum = s_b - n_b*t ;  t >= b+1 : sum = n_b*t - s_b,
// with s_b = n_b*b + fracsum_b*2^-25 (holds for b=0 and b=255 too).
__global__ void final_kernel(const int* __restrict__ counts,
                             const unsigned long long* __restrict__ fracs,
                             float* __restrict__ out) {
    __shared__ float cdf[6][NBINS];
    __shared__ int   lcnt[6 * NBINS];
    __shared__ double red[12];
    const int tid = threadIdx.x;           // 768 threads
    lcnt[tid]       = counts[tid];
    lcnt[tid + 768] = counts[tid + 768];
    __syncthreads();

    if (tid < 6) {
        // pdf = count / 2^20 is exact; serial f32 cumsum matches the reference
        float run = 0.0f;
        for (int i = 0; i < NBINS; ++i) {
            run += (float)lcnt[tid * NBINS + i] * (1.0f / KCNT);
            cdf[tid][i] = run;
        }
    }
    __syncthreads();

    const int c = tid >> 8, b = tid & (NBINS - 1);
    const float d = cdf[c][b];
    const float* r = cdf[3 + c];
    // searchsorted(r, d, side='left'): first j with r[j] >= d
    int lo = 0, hi = NBINS;
    while (lo < hi) {
        int mid = (lo + hi) >> 1;
        if (r[mid] < d) lo = mid + 1; else hi = mid;
    }
    int j = lo;
    if (j < 1) j = 1;
    if (j > NBINS - 1) j = NBINS - 1;
    bool valid = (r[j - 1] <= d) && (d <= r[j]);
    int t = valid ? j : b;
    if (b == NBINS - 1) t = NBINS - 1;

    const int n = lcnt[c * NBINS + b];
    const double s = (double)n * (double)b
                   + (double)(long long)fracs[c * NBINS + b] * FRAC_INV;
    double contrib = (t <= b) ? (s - (double)n * (double)t)
                              : ((double)n * (double)t - s);

    #pragma unroll
    for (int off = 32; off > 0; off >>= 1)
        contrib += __shfl_down(contrib, off, 64);
    const int wave = tid >> 6, lane = tid & 63;
    if (lane == 0) red[wave] = contrib;
    __syncthreads();
    if (tid == 0) {
        double tot = 0.0;
        for (int w = 0; w < 12; ++w) tot += red[w];
        out[0] = (float)(tot / TOTAL_ELEMS);
    }
}

extern "C" void kernel_launch(void* const* d_in, const int* in_sizes, int n_in,
                              void* d_out, int out_size, void* d_ws, size_t ws_size,
                              hipStream_t stream) {
    const float* inp  = (const float*)d_in[0];   // (1,3,H,H)
    const float* tar  = (const float*)d_in[1];   // (1,3,H,H)
    const float* msrc = (const float*)d_in[2];   // (1,1,H,H)
    const float* mtar = (const float*)d_in[3];   // (1,1,H,H)
    float* out = (float*)d_out;

    int nblk = 2048;   // 8 blocks/CU -> 32 waves/CU (full occupancy)
    if (ws_size < (size_t)nblk * ROW_BYTES + TAIL_BYTES) {
        size_t avail = ws_size > TAIL_BYTES ? (ws_size - TAIL_BYTES) / ROW_BYTES : 1;
        nblk = avail < 256 ? 256 : (int)avail;   // >=256 keeps pack fields safe
        if (nblk > 2048) nblk = 2048;
    }

    char* ws = (char*)d_ws;
    unsigned long long* parts = (unsigned long long*)ws;
    int*                counts = (int*)(ws + (size_t)nblk * ROW_BYTES);
    unsigned long long* fracs  = (unsigned long long*)(ws + (size_t)nblk * ROW_BYTES
                                                          + 1536 * sizeof(int));

    // zero only the small accumulator tail (atomic destinations)
    hipMemsetAsync((void*)counts, 0, TAIL_BYTES, stream);

    const int nchunks = (nblk + ROWS_PER_CHUNK - 1) / ROWS_PER_CHUNK;
    dim3 rgrid(6, nchunks);   // 1536 columns / 256 threads = 6

    hist_kernel<<<nblk, 256, 0, stream>>>(inp, tar, msrc, mtar, parts);
    reduce_kernel<<<rgrid, 256, 0, stream>>>(parts, nblk, counts, fracs);
    final_kernel<<<1, 3 * NBINS, 0, stream>>>(counts, fracs, out);
}

// Round 5
// 54.626 us; speedup vs baseline: 1.0132x; 1.0132x over previous
//
#include <hip/hip_runtime.h>
#include <hip/hip_bf16.h>

#define HDIM 2048
#define HH (HDIM * HDIM)          // 4,194,304 pixels per plane
#define NBINS 256
#define KCNT 1048576.0f           // K_SRC == K_TAR == HH/4 (exactly 2^20)
#define TOTAL_ELEMS 12582912.0    // 3 * H * H

// Pack layout for src bins: bits [63:40] = count, bits [39:0] = sum(frac * 2^25).
// Per block (8192 px, <=24576 src elems/bin): count < 2^24, fracsum < 2^40. OK.
#define FRAC_SCALE 33554432.0f    // 2^25
#define FRAC_INV   (1.0 / 33554432.0)
#define FRAC_MASK  ((1ull << 40) - 1)

#define NBLK 512                  // 8 grid-stride iterations/thread, exact
#define ROW_U64    1152           // 768 u64 (src packed) + 768 u32 (tar counts)
#define ROW_BYTES  9216
#define TAIL_BYTES (1536 * sizeof(int) + 768 * sizeof(unsigned long long))  // 12288
#define ROWS_PER_CHUNK 32

__device__ __forceinline__ float de_norm255(float x) {
    float v = (x + 1.0f) * 0.5f;               // /2.0 == *0.5 exactly in f32
    v = fminf(fmaxf(v, 0.0f), 1.0f) * 255.0f;  // in [0, 255]
    return v;
}

// Kernel 1: per-block histograms, conditional (exec-masked) LDS atomics,
// one packed u64 atomic per src element, register counters for clipped bins,
// 2-stage software prefetch over the 8 grid-stride iterations.
__global__ void __launch_bounds__(256) hist_kernel(
        const float* __restrict__ inp,
        const float* __restrict__ tar,
        const float* __restrict__ msrc,
        const float* __restrict__ mtar,
        unsigned long long* __restrict__ parts) {
    __shared__ unsigned long long h64[3 * NBINS];   // src: packed count|fracsum
    __shared__ unsigned int       h32[3 * NBINS];   // tar: counts
    for (int i = threadIdx.x; i < 3 * NBINS; i += blockDim.x) {
        h64[i] = 0ull;
        h32[i] = 0u;
    }
    __syncthreads();

    int nz[6] = {0, 0, 0, 0, 0, 0};   // v==0   counts (rows 0-2 src, 3-5 tar)
    int nf[6] = {0, 0, 0, 0, 0, 0};   // v==255 counts

    const int stride = NBLK * 256;                       // 131072
    const int tid0   = blockIdx.x * 256 + threadIdx.x;
    const float4* msrc4 = (const float4*)msrc;
    const float4* mtar4 = (const float4*)mtar;

    // stage 0: load iteration 0
    float4 ms = msrc4[tid0];
    float4 mt = mtar4[tid0];
    float4 a0 = ((const float4*)(inp + 0 * (size_t)HH))[tid0];
    float4 a1 = ((const float4*)(inp + 1 * (size_t)HH))[tid0];
    float4 a2 = ((const float4*)(inp + 2 * (size_t)HH))[tid0];
    float4 b0 = ((const float4*)(tar + 0 * (size_t)HH))[tid0];
    float4 b1 = ((const float4*)(tar + 1 * (size_t)HH))[tid0];
    float4 b2 = ((const float4*)(tar + 2 * (size_t)HH))[tid0];

    #pragma unroll 1
    for (int it = 0; it < 8; ++it) {
        // prefetch next iteration (last iter re-reads current: cached, discarded)
        const int pn = tid0 + ((it < 7) ? (it + 1) : it) * stride;
        float4 ms_n = msrc4[pn];
        float4 mt_n = mtar4[pn];
        float4 a0_n = ((const float4*)(inp + 0 * (size_t)HH))[pn];
        float4 a1_n = ((const float4*)(inp + 1 * (size_t)HH))[pn];
        float4 a2_n = ((const float4*)(inp + 2 * (size_t)HH))[pn];
        float4 b0_n = ((const float4*)(tar + 0 * (size_t)HH))[pn];
        float4 b1_n = ((const float4*)(tar + 1 * (size_t)HH))[pn];
        float4 b2_n = ((const float4*)(tar + 2 * (size_t)HH))[pn];

        const float m[4] = {ms.x, ms.y, ms.z, ms.w};
        const float t[4] = {mt.x, mt.y, mt.z, mt.w};
        const float4 av[3] = {a0, a1, a2};
        const float4 bv[3] = {b0, b1, b2};
        #pragma unroll
        for (int c = 0; c < 3; ++c) {
            const float vv[4] = {av[c].x, av[c].y, av[c].z, av[c].w};
            const float ww[4] = {bv[c].x, bv[c].y, bv[c].z, bv[c].w};
            #pragma unroll
            for (int k = 0; k < 4; ++k) {
                if (m[k] != 0.0f) {
                    float v = de_norm255(vv[k]);
                    if (v == 0.0f)        nz[c]++;
                    else if (v == 255.0f) nf[c]++;
                    else {
                        int bb = (int)v;
                        float frac = v - (float)bb;          // exact in f32
                        unsigned fx = (unsigned)(frac * FRAC_SCALE);
                        atomicAdd(&h64[c * NBINS + bb],
                                  (1ull << 40) | (unsigned long long)fx);
                    }
                }
                if (t[k] != 0.0f) {
                    float w = de_norm255(ww[k]);
                    if (w == 0.0f)        nz[3 + c]++;
                    else if (w == 255.0f) nf[3 + c]++;
                    else atomicAdd(&h32[c * NBINS + (int)w], 1u);
                }
            }
        }
        ms = ms_n; mt = mt_n;
        a0 = a0_n; a1 = a1_n; a2 = a2_n;
        b0 = b0_n; b1 = b1_n; b2 = b2_n;
    }

    // wave-reduce the 12 clipped-value counters, one LDS atomic per wave each
    const int lane = threadIdx.x & 63;
    #pragma unroll
    for (int j = 0; j < 6; ++j) {
        int a = nz[j], f = nf[j];
        #pragma unroll
        for (int off = 32; off > 0; off >>= 1) {
            a += __shfl_down(a, off, 64);
            f += __shfl_down(f, off, 64);
        }
        if (lane == 0) {
            if (j < 3) {
                if (a) atomicAdd(&h64[j * NBINS + 0],
                                 ((unsigned long long)a) << 40);
                if (f) atomicAdd(&h64[j * NBINS + NBINS - 1],
                                 ((unsigned long long)f) << 40);
            } else {
                if (a) atomicAdd(&h32[(j - 3) * NBINS + 0], (unsigned)a);
                if (f) atomicAdd(&h32[(j - 3) * NBINS + NBINS - 1], (unsigned)f);
            }
        }
    }
    __syncthreads();

    // coalesced flush of this block's partial row (full overwrite -> no memset)
    unsigned long long* row64 = parts + (size_t)blockIdx.x * ROW_U64;
    for (int i = threadIdx.x; i < 3 * NBINS; i += blockDim.x)
        row64[i] = h64[i];
    unsigned int* row32 = (unsigned int*)(row64 + 3 * NBINS);
    for (int i = threadIdx.x; i < 3 * NBINS; i += blockDim.x)
        row32[i] = h32[i];
}

// Kernel 2: column reduction over row-chunks; integer atomics -> deterministic.
__global__ void reduce_kernel(const unsigned long long* __restrict__ parts,
                              int nblk,
                              int* __restrict__ counts,              // [1536]
                              unsigned long long* __restrict__ fracs) { // [768]
    const int j = blockIdx.x * blockDim.x + threadIdx.x;   // column 0..1535
    if (j >= 1536) return;
    int w0 = blockIdx.y * ROWS_PER_CHUNK;
    int w1 = w0 + ROWS_PER_CHUNK;
    if (w1 > nblk) w1 = nblk;
    if (w0 >= w1) return;

    if (j < 768) {
        unsigned long long cnt = 0, fr = 0;
        for (int w = w0; w < w1; ++w) {
            unsigned long long p = parts[(size_t)w * ROW_U64 + j];
            cnt += p >> 40;
            fr  += p & FRAC_MASK;
        }
        if (cnt) atomicAdd(&counts[j], (int)cnt);
        if (fr)  atomicAdd(&fracs[j], fr);
    } else {
        const unsigned int* p32 = (const unsigned int*)parts;
        int cnt = 0;
        const int jj = j - 768;
        for (int w = w0; w < w1; ++w)
            cnt += p32[(size_t)w * (2 * ROW_U64) + 1536 + jj];
        if (cnt) atomicAdd(&counts[768 + jj], cnt);
    }
}

// Kernel 3: cdf (bit-exact serial f32 cumsum) + searchsorted table + analytic loss.
// Within bin b, v in [b, b+1) and t integer => |v-t| sign fixed per bin:
//   t <= b : sum = s_b - n_b*t ;  t >= b+1 : sum = n_b*t - s_b,
// with s_b = n_b*b + fracsum_b*2^-25 (holds for b=0 and b=255 too).
__global__ void final_kernel(const int* __restrict__ counts,
                             const unsigned long long* __restrict__ fracs,
                             float* __restrict__ out) {
    __shared__ float cdf[6][NBINS];
    __shared__ int   lcnt[6 * NBINS];
    __shared__ double red[12];
    const int tid = threadIdx.x;           // 768 threads
    lcnt[tid]       = counts[tid];
    lcnt[tid + 768] = counts[tid + 768];
    __syncthreads();

    if (tid < 6) {
        // pdf = count / 2^20 is exact; serial f32 cumsum matches the reference
        float run = 0.0f;
        for (int i = 0; i < NBINS; ++i) {
            run += (float)lcnt[tid * NBINS + i] * (1.0f / KCNT);
            cdf[tid][i] = run;
        }
    }
    __syncthreads();

    const int c = tid >> 8, b = tid & (NBINS - 1);
    const float d = cdf[c][b];
    const float* r = cdf[3 + c];
    // searchsorted(r, d, side='left'): first j with r[j] >= d
    int lo = 0, hi = NBINS;
    while (lo < hi) {
        int mid = (lo + hi) >> 1;
        if (r[mid] < d) lo = mid + 1; else hi = mid;
    }
    int j = lo;
    if (j < 1) j = 1;
    if (j > NBINS - 1) j = NBINS - 1;
    bool valid = (r[j - 1] <= d) && (d <= r[j]);
    int t = valid ? j : b;
    if (b == NBINS - 1) t = NBINS - 1;

    const int n = lcnt[c * NBINS + b];
    const double s = (double)n * (double)b
                   + (double)(long long)fracs[c * NBINS + b] * FRAC_INV;
    double contrib = (t <= b) ? (s - (double)n * (double)t)
                              : ((double)n * (double)t - s);

    #pragma unroll
    for (int off = 32; off > 0; off >>= 1)
        contrib += __shfl_down(contrib, off, 64);
    const int wave = tid >> 6, lane = tid & 63;
    if (lane == 0) red[wave] = contrib;
    __syncthreads();
    if (tid == 0) {
        double tot = 0.0;
        for (int w = 0; w < 12; ++w) tot += red[w];
        out[0] = (float)(tot / TOTAL_ELEMS);
    }
}

extern "C" void kernel_launch(void* const* d_in, const int* in_sizes, int n_in,
                              void* d_out, int out_size, void* d_ws, size_t ws_size,
                              hipStream_t stream) {
    const float* inp  = (const float*)d_in[0];   // (1,3,H,H)
    const float* tar  = (const float*)d_in[1];   // (1,3,H,H)
    const float* msrc = (const float*)d_in[2];   // (1,1,H,H)
    const float* mtar = (const float*)d_in[3];   // (1,1,H,H)
    float* out = (float*)d_out;

    char* ws = (char*)d_ws;
    unsigned long long* parts = (unsigned long long*)ws;
    int*                counts = (int*)(ws + (size_t)NBLK * ROW_BYTES);
    unsigned long long* fracs  = (unsigned long long*)(ws + (size_t)NBLK * ROW_BYTES
                                                          + 1536 * sizeof(int));

    // zero only the small accumulator tail (atomic destinations)
    hipMemsetAsync((void*)counts, 0, TAIL_BYTES, stream);

    const int nchunks = (NBLK + ROWS_PER_CHUNK - 1) / ROWS_PER_CHUNK;
    dim3 rgrid(6, nchunks);   // 1536 columns / 256 threads = 6

    hist_kernel<<<NBLK, 256, 0, stream>>>(inp, tar, msrc, mtar, parts);
    reduce_kernel<<<rgrid, 256, 0, stream>>>(parts, NBLK, counts, fracs);
    final_kernel<<<1, 3 * NBINS, 0, stream>>>(counts, fracs, out);
}